// Round 10
// baseline (140.710 us; speedup 1.0000x reference)
//
#include <hip/hip_runtime.h>

// VQ-VAE VectorQuantizer forward, MI355X (gfx950)
// inputs:  d_in[0] = inputs  [64,32,32,64] f32  (N=65536 rows, D=64)
//          d_in[1] = context [1] (unused)
//          d_in[2] = embeddings [64,512] f32    (D=64, K=512)
// out (flat f32): quantized[4194304] | loss[1] | perplexity[1] |
//   encodings[33554432] | encoding_indices[65536] | distances[33554432]

#define NROWS 65536
#define DIM 64
#define KCODES 512
#define ROWS_PER_BLOCK 128
#define NBLOCKS (NROWS / ROWS_PER_BLOCK)   // 512
#define RPT 4                               // rows per K-pass (fine store grain)
#define NGRP 4                              // K-passes per wave (16 rows/wave)

#define QUANT_OFF 0ull
#define LOSS_OFF  4194304ull
#define PERP_OFF  4194305ull
#define ENC_OFF   4194306ull
#define IDX_OFF   37748738ull
#define DIST_OFF  37814274ull

typedef float f32x4 __attribute__((ext_vector_type(4)));

// ---- K0: transpose E[64][512] -> ET[512][64] in workspace (~2us, once)
__global__ __launch_bounds__(64) void vq_transpose(
    const float* __restrict__ emb, float* __restrict__ et)
{
    const int t = blockIdx.x * 64 + threadIdx.x;   // one k per thread
    f32x4* et4 = (f32x4*)et;                       // [512][16]
#pragma unroll
    for (int dq = 0; dq < 16; ++dq) {
        f32x4 v;
        v.x = emb[(dq * 4 + 0) * KCODES + t];      // coalesced per d
        v.y = emb[(dq * 4 + 1) * KCODES + t];
        v.z = emb[(dq * 4 + 2) * KCODES + t];
        v.w = emb[(dq * 4 + 3) * KCODES + t];
        et4[t * 16 + dq] = v;
    }
}

// ---- K1: main fused kernel. ONE barrier before any store; then free-run.
//      4-row K-passes keep the store stream fine-grained; plain (L2-routed)
//      stores let L2 absorb bursts and write back smoothly.
__global__ __launch_bounds__(512, 4) void vq_main(
    const float* __restrict__ inp, const float* __restrict__ emb,
    const float* __restrict__ et,
    float* __restrict__ out, float* __restrict__ loss_part)
{
    __shared__ f32x4 s_X[ROWS_PER_BLOCK * 16];    // 32 KB [row][dq]
    __shared__ float s_sumx2[ROWS_PER_BLOCK];
    __shared__ float s_loss[8];

    const int tid  = threadIdx.x;
    const int w    = tid >> 6;                    // wave 0..7
    const int lane = tid & 63;
    const int rbase = blockIdx.x * ROWS_PER_BLOCK;
    // lane owns k = h*256 + lane*4 + j  (h=0,1; j=0..3)

    // ---- stage all 128 rows of x -> LDS (coalesced b128, linear) ----
    {
        const f32x4* inp4 = (const f32x4*)inp;
#pragma unroll
        for (int i = 0; i < 4; ++i)
            s_X[i * 512 + tid] = inp4[(size_t)blockIdx.x * 2048 + i * 512 + tid];
    }
    __syncthreads();   // the ONLY barrier before the store streams start

    // ---- per-row ||x||^2 for THIS wave's 16 rows (no further barrier) ----
    {
        const int row_l = w * 16 + (lane >> 2);
        const int q = lane & 3;
        float p = 0.f;
#pragma unroll
        for (int j = 0; j < 4; ++j) {
            const f32x4 v = s_X[row_l * 16 + q * 4 + j];
            p = fmaf(v.x, v.x, p); p = fmaf(v.y, v.y, p);
            p = fmaf(v.z, v.z, p); p = fmaf(v.w, v.w, p);
        }
        p += __shfl_xor(p, 1);
        p += __shfl_xor(p, 2);
        if (q == 0) s_sumx2[row_l] = p;           // same wave reads it later
    }

    f32x4 sume2_0 = {0.f, 0.f, 0.f, 0.f};
    f32x4 sume2_1 = {0.f, 0.f, 0.f, 0.f};
    float loss_acc = 0.f;

    const float* ebase = emb + lane * 4;
    const f32x4* et4 = (const f32x4*)et;

#pragma unroll 1
    for (int gi = 0; gi < NGRP; ++gi) {
        const int g   = (gi + w) & 3;             // de-correlate wave phases
        const int rl0 = w * 16 + g * RPT;         // block-local row base

        f32x4 acc[RPT][2];
#pragma unroll
        for (int r = 0; r < RPT; ++r) {
            acc[r][0] = (f32x4){0.f, 0.f, 0.f, 0.f};
            acc[r][1] = (f32x4){0.f, 0.f, 0.f, 0.f};
        }

#pragma unroll 1
        for (int dq = 0; dq < 16; ++dq) {
            f32x4 e0[4], e1[4];
#pragma unroll
            for (int sub = 0; sub < 4; ++sub) {
                e0[sub] = *(const f32x4*)(ebase + (dq * 4 + sub) * KCODES);
                e1[sub] = *(const f32x4*)(ebase + (dq * 4 + sub) * KCODES + 256);
            }
            if (gi == 0) {                        // fold ||e||^2 into 1st pass
#pragma unroll
                for (int sub = 0; sub < 4; ++sub) {
                    sume2_0 = sume2_0 + e0[sub] * e0[sub];
                    sume2_1 = sume2_1 + e1[sub] * e1[sub];
                }
            }
#pragma unroll
            for (int r = 0; r < RPT; ++r) {
                const f32x4 xv = s_X[(rl0 + r) * 16 + dq];   // DS broadcast
                acc[r][0] = acc[r][0] + xv.x * e0[0];
                acc[r][1] = acc[r][1] + xv.x * e1[0];
                acc[r][0] = acc[r][0] + xv.y * e0[1];
                acc[r][1] = acc[r][1] + xv.y * e1[1];
                acc[r][0] = acc[r][0] + xv.z * e0[2];
                acc[r][1] = acc[r][1] + xv.z * e1[2];
                acc[r][0] = acc[r][0] + xv.w * e0[3];
                acc[r][1] = acc[r][1] + xv.w * e1[3];
            }
        }

        // ---- epilogue: distances, argmin, stores (plain, L2-buffered) ----
#pragma unroll
        for (int r = 0; r < RPT; ++r) {
            const int row = rbase + rl0 + r;
            const float sx2 = s_sumx2[rl0 + r];

            const f32x4 dd0 = (sume2_0 + sx2) + (-2.f) * acc[r][0];
            const f32x4 dd1 = (sume2_1 + sx2) + (-2.f) * acc[r][1];

            f32x4* dp = (f32x4*)(out + DIST_OFF) + (size_t)row * 128;
            dp[lane]      = dd0;
            dp[64 + lane] = dd1;

            // per-lane min + smallest index, then cross-lane
            float bd = fminf(fminf(fminf(dd0.x, dd0.y), fminf(dd0.z, dd0.w)),
                             fminf(fminf(dd1.x, dd1.y), fminf(dd1.z, dd1.w)));
            const int kb = lane * 4;
            int ck = 0x7fffffff;
            if (dd1.w == bd) ck = 256 + kb + 3;
            if (dd1.z == bd) ck = 256 + kb + 2;
            if (dd1.y == bd) ck = 256 + kb + 1;
            if (dd1.x == bd) ck = 256 + kb + 0;
            if (dd0.w == bd) ck = kb + 3;
            if (dd0.z == bd) ck = kb + 2;
            if (dd0.y == bd) ck = kb + 1;
            if (dd0.x == bd) ck = kb + 0;

            float fd = bd;
#pragma unroll
            for (int off = 32; off; off >>= 1)
                fd = fminf(fd, __shfl_xor(fd, off));
            int c2 = (bd == fd) ? ck : 0x7fffffff;
#pragma unroll
            for (int off = 32; off; off >>= 1) {
                const int ok = __shfl_xor(c2, off);
                c2 = ok < c2 ? ok : c2;
            }

            // encodings one-hot: 2 contiguous f32x4 stores
            f32x4* ep = (f32x4*)(out + ENC_OFF) + (size_t)row * 128;
            const int cq = c2 >> 2;
            f32x4 v0 = {0.f, 0.f, 0.f, 0.f};
            f32x4 v1 = {0.f, 0.f, 0.f, 0.f};
            if (cq == lane) {
                v0.x = (c2 & 3) == 0 ? 1.f : 0.f;
                v0.y = (c2 & 3) == 1 ? 1.f : 0.f;
                v0.z = (c2 & 3) == 2 ? 1.f : 0.f;
                v0.w = (c2 & 3) == 3 ? 1.f : 0.f;
            }
            if (cq == 64 + lane) {
                v1.x = (c2 & 3) == 0 ? 1.f : 0.f;
                v1.y = (c2 & 3) == 1 ? 1.f : 0.f;
                v1.z = (c2 & 3) == 2 ? 1.f : 0.f;
                v1.w = (c2 & 3) == 3 ? 1.f : 0.f;
            }
            ep[lane]      = v0;
            ep[64 + lane] = v1;

            // quantized row from ET: 16 lanes x f32x4, 256 B (L2-hot)
            if (lane < 16) {
                const f32x4 q = et4[c2 * 16 + lane];
                ((f32x4*)(out + QUANT_OFF + (size_t)row * DIM))[lane] = q;
            }

            if (lane == 0) {
                out[IDX_OFF + row] = (float)c2;
                loss_acc += fd;                   // sum_d(q-x)^2 == min dist
            }
        }
    }

    // ---- loss: deterministic per-block partial ----
    if (lane == 0) s_loss[w] = loss_acc;
    __syncthreads();
    if (tid == 0) {
        float s = 0.f;
#pragma unroll
        for (int i = 0; i < 8; ++i) s += s_loss[i];
        loss_part[blockIdx.x] = s;
    }
}

// ---- K2: histogram from indices (per-wave LDS sub-hists), perplexity, loss
__global__ __launch_bounds__(512) void vq_final(
    const float* __restrict__ out_ro, const float* __restrict__ loss_part,
    float* __restrict__ out)
{
    __shared__ int   s_hist[8][KCODES];   // 16 KB
    __shared__ float s_red[8];
    __shared__ float s_red2[8];
    const int tid = threadIdx.x;
    const int w = tid >> 6, lane = tid & 63;

#pragma unroll
    for (int i = 0; i < 8; ++i) ((int*)s_hist)[i * 512 + tid] = 0;
    __syncthreads();

    const float* idx_f = out_ro + IDX_OFF;
#pragma unroll 4
    for (int i = 0; i < 128; ++i) {
        const int idx = (int)idx_f[i * 512 + tid];   // coalesced
        atomicAdd(&s_hist[w][idx], 1);               // wave-private -> low contention
    }
    __syncthreads();

    int cnt = 0;
#pragma unroll
    for (int h = 0; h < 8; ++h) cnt += s_hist[h][tid];

    float p = (float)cnt * (1.f / 65536.f);
    float t = p * logf(p + 1e-10f);   // p==0 -> 0
    float l = loss_part[tid];         // 512 partials, fixed order
#pragma unroll
    for (int off = 32; off; off >>= 1) {
        t += __shfl_xor(t, off);
        l += __shfl_xor(l, off);
    }
    if (lane == 0) { s_red[w] = t; s_red2[w] = l; }
    __syncthreads();
    if (tid == 0) {
        float s = 0.f, ls = 0.f;
#pragma unroll
        for (int i = 0; i < 8; ++i) { s += s_red[i]; ls += s_red2[i]; }
        out[PERP_OFF] = expf(-s);
        // loss = (1 + 0.25) * mean((q - x)^2) over 4194304 elements
        out[LOSS_OFF] = ls * (1.25f / 4194304.f);
    }
}

extern "C" void kernel_launch(void* const* d_in, const int* in_sizes, int n_in,
                              void* d_out, int out_size, void* d_ws, size_t ws_size,
                              hipStream_t stream) {
    const float* inp = (const float*)d_in[0];
    const float* emb = (const float*)d_in[2];
    float* out = (float*)d_out;
    float* loss_part = (float*)((char*)d_ws + 2048);   // 512 floats @ 2048
    float* et        = (float*)((char*)d_ws + 8192);   // 128 KB ET  @ 8192

    vq_transpose<<<dim3(8), dim3(64), 0, stream>>>(emb, et);
    vq_main<<<dim3(NBLOCKS), dim3(512), 0, stream>>>(
        inp, emb, et, out, loss_part);
    vq_final<<<dim3(1), dim3(512), 0, stream>>>(out, loss_part, out);
}

// Round 11
// 112.644 us; speedup vs baseline: 1.2492x; 1.2492x over previous
//
#include <hip/hip_runtime.h>

// VQ-VAE VectorQuantizer forward, MI355X (gfx950)
// inputs:  d_in[0] = inputs  [64,32,32,64] f32  (N=65536 rows, D=64)
//          d_in[1] = context [1] (unused)
//          d_in[2] = embeddings [64,512] f32    (D=64, K=512)
// out (flat f32): quantized[4194304] | loss[1] | perplexity[1] |
//   encodings[33554432] | encoding_indices[65536] | distances[33554432]

#define NROWS 65536
#define DIM 64
#define KCODES 512
#define ROWS_PER_BLOCK 64
#define NBLOCKS (NROWS / ROWS_PER_BLOCK)   // 1024
#define RPW 8                               // rows per wave (one full-K pass)

#define QUANT_OFF 0ull
#define LOSS_OFF  4194304ull
#define PERP_OFF  4194305ull
#define ENC_OFF   4194306ull
#define IDX_OFF   37748738ull
#define DIST_OFF  37814274ull

typedef float f32x4 __attribute__((ext_vector_type(4)));

// ---- K0: transpose E[64][512] -> ET[512][64] in ws (for quant gather)
__global__ __launch_bounds__(64) void vq_transpose(
    const float* __restrict__ emb, float* __restrict__ et)
{
    const int t = blockIdx.x * 64 + threadIdx.x;   // one k per thread
    f32x4* et4 = (f32x4*)et;                       // [512][16]
#pragma unroll
    for (int dq = 0; dq < 16; ++dq) {
        f32x4 v;
        v.x = emb[(dq * 4 + 0) * KCODES + t];      // coalesced per d
        v.y = emb[(dq * 4 + 1) * KCODES + t];
        v.z = emb[(dq * 4 + 2) * KCODES + t];
        v.w = emb[(dq * 4 + 3) * KCODES + t];
        et4[t * 16 + dq] = v;
    }
}

// ---- K1: main kernel. E + X fully in LDS -> dq loop is DS/VALU only,
//      so vmcnt carries ONLY stores (never waited on until kernel end).
//      One barrier total, before any store exists.
__global__ __launch_bounds__(512, 2) void vq_main(
    const float* __restrict__ inp, const float* __restrict__ emb,
    const float* __restrict__ et,
    float* __restrict__ out, int* __restrict__ hist,
    float* __restrict__ loss_part)
{
    __shared__ f32x4 s_E[16 * KCODES];            // 128 KB, identity copy of emb
    __shared__ f32x4 s_X[ROWS_PER_BLOCK * 16];    // 16 KB [row][dq]
    __shared__ float s_sumx2[ROWS_PER_BLOCK];
    __shared__ float s_loss[8];

    const int tid  = threadIdx.x;
    const int w    = tid >> 6;                    // wave 0..7
    const int lane = tid & 63;
    const int rbase = blockIdx.x * ROWS_PER_BLOCK;
    const int rl0  = w * RPW;                     // block-local row base
    // lane owns k = h*256 + lane*4 + j  (h=0,1; j=0..3)

    // ---- stage E -> LDS: straight linear copy (coalesced, conflict-free).
    //      s_E[d*128 + kq] = {E[d][4kq..4kq+3]}  (identity f32x4 view of emb)
    {
        const f32x4* e4 = (const f32x4*)emb;
#pragma unroll
        for (int i = 0; i < 16; ++i)
            s_E[i * 512 + tid] = e4[i * 512 + tid];
    }
    // ---- stage X (64 rows) -> LDS, linear ----
    {
        const f32x4* inp4 = (const f32x4*)inp + (size_t)blockIdx.x * 1024;
        s_X[tid]       = inp4[tid];
        s_X[512 + tid] = inp4[512 + tid];
    }
    __syncthreads();   // the ONLY barrier; no store issued yet

    // ---- per-row ||x||^2 for THIS wave's 8 rows (8 lanes per row) ----
    {
        const int row_l = w * RPW + (lane >> 3);
        const int q = lane & 7;
        const f32x4 a = s_X[row_l * 16 + q * 2 + 0];
        const f32x4 b = s_X[row_l * 16 + q * 2 + 1];
        float p = 0.f;
        p = fmaf(a.x, a.x, p); p = fmaf(a.y, a.y, p);
        p = fmaf(a.z, a.z, p); p = fmaf(a.w, a.w, p);
        p = fmaf(b.x, b.x, p); p = fmaf(b.y, b.y, p);
        p = fmaf(b.z, b.z, p); p = fmaf(b.w, b.w, p);
        p += __shfl_xor(p, 1);
        p += __shfl_xor(p, 2);
        p += __shfl_xor(p, 4);
        if (q == 0) s_sumx2[row_l] = p;           // same wave reads it later
    }

    f32x4 sume2_0 = {0.f, 0.f, 0.f, 0.f};
    f32x4 sume2_1 = {0.f, 0.f, 0.f, 0.f};
    float loss_acc = 0.f;

    f32x4 acc[RPW][2];
#pragma unroll
    for (int r = 0; r < RPW; ++r) {
        acc[r][0] = (f32x4){0.f, 0.f, 0.f, 0.f};
        acc[r][1] = (f32x4){0.f, 0.f, 0.f, 0.f};
    }

    // ---- one full-K pass over this wave's 8 rows; all operands from LDS ----
#pragma unroll 1
    for (int dq = 0; dq < 16; ++dq) {
        f32x4 e0[4], e1[4];
#pragma unroll
        for (int sub = 0; sub < 4; ++sub) {
            e0[sub] = s_E[(dq * 4 + sub) * 128 + lane];        // k=lane*4+j
            e1[sub] = s_E[(dq * 4 + sub) * 128 + 64 + lane];   // k=256+lane*4+j
        }
#pragma unroll
        for (int sub = 0; sub < 4; ++sub) {       // fold ||e||^2 (single pass)
            sume2_0 = sume2_0 + e0[sub] * e0[sub];
            sume2_1 = sume2_1 + e1[sub] * e1[sub];
        }
#pragma unroll
        for (int r = 0; r < RPW; ++r) {
            const f32x4 xv = s_X[(rl0 + r) * 16 + dq];   // DS broadcast
            acc[r][0] = acc[r][0] + xv.x * e0[0];
            acc[r][1] = acc[r][1] + xv.x * e1[0];
            acc[r][0] = acc[r][0] + xv.y * e0[1];
            acc[r][1] = acc[r][1] + xv.y * e1[1];
            acc[r][0] = acc[r][0] + xv.z * e0[2];
            acc[r][1] = acc[r][1] + xv.z * e1[2];
            acc[r][0] = acc[r][0] + xv.w * e0[3];
            acc[r][1] = acc[r][1] + xv.w * e1[3];
        }
    }

    const f32x4* et4 = (const f32x4*)et;

    // ---- epilogue: distances, argmin, NT stores (never drained mid-kernel) ----
#pragma unroll
    for (int r = 0; r < RPW; ++r) {
        const int row = rbase + rl0 + r;
        const float sx2 = s_sumx2[rl0 + r];

        const f32x4 dd0 = (sume2_0 + sx2) + (-2.f) * acc[r][0];
        const f32x4 dd1 = (sume2_1 + sx2) + (-2.f) * acc[r][1];

        f32x4* dp = (f32x4*)(out + DIST_OFF) + (size_t)row * 128;
        __builtin_nontemporal_store(dd0, dp + lane);
        __builtin_nontemporal_store(dd1, dp + 64 + lane);

        // per-lane min + smallest index, then cross-lane
        float bd = fminf(fminf(fminf(dd0.x, dd0.y), fminf(dd0.z, dd0.w)),
                         fminf(fminf(dd1.x, dd1.y), fminf(dd1.z, dd1.w)));
        const int kb = lane * 4;
        int ck = 0x7fffffff;
        if (dd1.w == bd) ck = 256 + kb + 3;
        if (dd1.z == bd) ck = 256 + kb + 2;
        if (dd1.y == bd) ck = 256 + kb + 1;
        if (dd1.x == bd) ck = 256 + kb + 0;
        if (dd0.w == bd) ck = kb + 3;
        if (dd0.z == bd) ck = kb + 2;
        if (dd0.y == bd) ck = kb + 1;
        if (dd0.x == bd) ck = kb + 0;

        float fd = bd;
#pragma unroll
        for (int off = 32; off; off >>= 1)
            fd = fminf(fd, __shfl_xor(fd, off));
        int c2 = (bd == fd) ? ck : 0x7fffffff;
#pragma unroll
        for (int off = 32; off; off >>= 1) {
            const int ok = __shfl_xor(c2, off);
            c2 = ok < c2 ? ok : c2;
        }

        // encodings one-hot: 2 contiguous f32x4 NT stores
        f32x4* ep = (f32x4*)(out + ENC_OFF) + (size_t)row * 128;
        const int cq = c2 >> 2;
        f32x4 v0 = {0.f, 0.f, 0.f, 0.f};
        f32x4 v1 = {0.f, 0.f, 0.f, 0.f};
        if (cq == lane) {
            v0.x = (c2 & 3) == 0 ? 1.f : 0.f;
            v0.y = (c2 & 3) == 1 ? 1.f : 0.f;
            v0.z = (c2 & 3) == 2 ? 1.f : 0.f;
            v0.w = (c2 & 3) == 3 ? 1.f : 0.f;
        }
        if (cq == 64 + lane) {
            v1.x = (c2 & 3) == 0 ? 1.f : 0.f;
            v1.y = (c2 & 3) == 1 ? 1.f : 0.f;
            v1.z = (c2 & 3) == 2 ? 1.f : 0.f;
            v1.w = (c2 & 3) == 3 ? 1.f : 0.f;
        }
        __builtin_nontemporal_store(v0, ep + lane);
        __builtin_nontemporal_store(v1, ep + 64 + lane);

        // quantized row from pre-transposed ET: 16 lanes x f32x4 (L2-hot)
        if (lane < 16) {
            const f32x4 q = et4[c2 * 16 + lane];
            ((f32x4*)(out + QUANT_OFF + (size_t)row * DIM))[lane] = q;
        }

        if (lane == 0) {
            out[IDX_OFF + row] = (float)c2;
            atomicAdd(&hist[c2], 1);
            loss_acc += fd;                       // sum_d(q-x)^2 == min dist
        }
    }

    // ---- loss: deterministic per-block partial ----
    if (lane == 0) s_loss[w] = loss_acc;
    __syncthreads();
    if (tid == 0) {
        float s = 0.f;
#pragma unroll
        for (int i = 0; i < 8; ++i) s += s_loss[i];
        loss_part[blockIdx.x] = s;
    }
}

__global__ __launch_bounds__(512) void vq_final(
    const int* __restrict__ hist, const float* __restrict__ loss_part,
    float* __restrict__ out)
{
    __shared__ float s_red[8];
    __shared__ float s_red2[8];
    const int tid = threadIdx.x;
    const int w = tid >> 6, lane = tid & 63;

    float p = (float)hist[tid] * (1.f / 65536.f);
    float t = p * logf(p + 1e-10f);   // p==0 -> 0
    float l = loss_part[tid] + loss_part[tid + 512];   // 1024 partials
#pragma unroll
    for (int off = 32; off; off >>= 1) {
        t += __shfl_xor(t, off);
        l += __shfl_xor(l, off);
    }
    if (lane == 0) { s_red[w] = t; s_red2[w] = l; }
    __syncthreads();
    if (tid == 0) {
        float s = 0.f, ls = 0.f;
#pragma unroll
        for (int i = 0; i < 8; ++i) { s += s_red[i]; ls += s_red2[i]; }
        out[PERP_OFF] = expf(-s);
        // loss = (1 + 0.25) * mean((q - x)^2) over 4194304 elements
        out[LOSS_OFF] = ls * (1.25f / 4194304.f);
    }
}

extern "C" void kernel_launch(void* const* d_in, const int* in_sizes, int n_in,
                              void* d_out, int out_size, void* d_ws, size_t ws_size,
                              hipStream_t stream) {
    const float* inp = (const float*)d_in[0];
    const float* emb = (const float*)d_in[2];
    float* out = (float*)d_out;
    int*   hist      = (int*)d_ws;                     // 512 ints    @ 0
    float* loss_part = (float*)((char*)d_ws + 2048);   // 1024 floats @ 2048
    float* et        = (float*)((char*)d_ws + 8192);   // 128 KB ET   @ 8192

    (void)hipMemsetAsync(d_ws, 0, 2048, stream);       // hist only
    vq_transpose<<<dim3(8), dim3(64), 0, stream>>>(emb, et);
    vq_main<<<dim3(NBLOCKS), dim3(512), 0, stream>>>(
        inp, emb, et, out, hist, loss_part);
    vq_final<<<dim3(1), dim3(512), 0, stream>>>(hist, loss_part, out);
}

// Round 12
// 107.667 us; speedup vs baseline: 1.3069x; 1.0462x over previous
//
#include <hip/hip_runtime.h>

// VQ-VAE VectorQuantizer forward, MI355X (gfx950)
// inputs:  d_in[0] = inputs  [64,32,32,64] f32  (N=65536 rows, D=64)
//          d_in[1] = context [1] (unused)
//          d_in[2] = embeddings [64,512] f32    (D=64, K=512)
// out (flat f32): quantized[4194304] | loss[1] | perplexity[1] |
//   encodings[33554432] | encoding_indices[65536] | distances[33554432]

#define NROWS 65536
#define DIM 64
#define KCODES 512
#define ROWS_PER_BLOCK 64
#define NBLOCKS (NROWS / ROWS_PER_BLOCK)   // 1024
#define RPW 8                               // rows per wave (single full-K pass)

#define QUANT_OFF 0ull
#define LOSS_OFF  4194304ull
#define PERP_OFF  4194305ull
#define ENC_OFF   4194306ull
#define IDX_OFF   37748738ull
#define DIST_OFF  37814274ull

typedef float f32x4 __attribute__((ext_vector_type(4)));

// ---- K0: transpose E[64][512] -> ET[512][64] in ws (for quant gather)
__global__ __launch_bounds__(64) void vq_transpose(
    const float* __restrict__ emb, float* __restrict__ et)
{
    const int t = blockIdx.x * 64 + threadIdx.x;   // one k per thread
    f32x4* et4 = (f32x4*)et;                       // [512][16]
#pragma unroll
    for (int dq = 0; dq < 16; ++dq) {
        f32x4 v;
        v.x = emb[(dq * 4 + 0) * KCODES + t];      // coalesced per d
        v.y = emb[(dq * 4 + 1) * KCODES + t];
        v.z = emb[(dq * 4 + 2) * KCODES + t];
        v.w = emb[(dq * 4 + 3) * KCODES + t];
        et4[t * 16 + dq] = v;
    }
}

// ---- K1: single-pass kernel. Loads-then-stores discipline: NO load is ever
//      issued after a store, so vmcnt waits never force a store drain.
//      Block-level pipelining (2 blocks/CU) overlaps compute with the
//      previous block's store drain.
__global__ __launch_bounds__(512, 4) void vq_main(
    const float* __restrict__ inp, const float* __restrict__ emb,
    const float* __restrict__ et,
    float* __restrict__ out, int* __restrict__ hist,
    float* __restrict__ loss_part)
{
    __shared__ f32x4 s_X[ROWS_PER_BLOCK * 16];    // 16 KB [row][dq]
    __shared__ float s_sumx2[ROWS_PER_BLOCK];
    __shared__ float s_loss[8];

    const int tid  = threadIdx.x;
    const int w    = tid >> 6;                    // wave 0..7
    const int lane = tid & 63;
    const int rbase = blockIdx.x * ROWS_PER_BLOCK;
    const int rl0  = w * RPW;                     // block-local row base
    // lane owns k = h*256 + lane*4 + j  (h=0,1; j=0..3)

    // ---- stage X (64 rows) -> LDS, linear coalesced b128 ----
    {
        const f32x4* inp4 = (const f32x4*)inp + (size_t)blockIdx.x * 1024;
        s_X[tid]       = inp4[tid];
        s_X[512 + tid] = inp4[512 + tid];
    }
    __syncthreads();   // the ONLY barrier; no store issued yet

    // ---- per-row ||x||^2 for THIS wave's 8 rows (8 lanes per row) ----
    {
        const int row_l = w * RPW + (lane >> 3);
        const int q = lane & 7;
        const f32x4 a = s_X[row_l * 16 + q * 2 + 0];
        const f32x4 b = s_X[row_l * 16 + q * 2 + 1];
        float p = 0.f;
        p = fmaf(a.x, a.x, p); p = fmaf(a.y, a.y, p);
        p = fmaf(a.z, a.z, p); p = fmaf(a.w, a.w, p);
        p = fmaf(b.x, b.x, p); p = fmaf(b.y, b.y, p);
        p = fmaf(b.z, b.z, p); p = fmaf(b.w, b.w, p);
        p += __shfl_xor(p, 1);
        p += __shfl_xor(p, 2);
        p += __shfl_xor(p, 4);
        if (q == 0) s_sumx2[row_l] = p;           // same wave reads it later
    }

    f32x4 sume2_0 = {0.f, 0.f, 0.f, 0.f};
    f32x4 sume2_1 = {0.f, 0.f, 0.f, 0.f};
    float loss_acc = 0.f;

    f32x4 acc[RPW][2];
#pragma unroll
    for (int r = 0; r < RPW; ++r) {
        acc[r][0] = (f32x4){0.f, 0.f, 0.f, 0.f};
        acc[r][1] = (f32x4){0.f, 0.f, 0.f, 0.f};
    }

    const float* ebase = emb + lane * 4;

    // ---- one full-K pass; E from global (L2-hot), X via DS broadcast ----
#pragma unroll 1
    for (int dq = 0; dq < 16; ++dq) {
        f32x4 e0[4], e1[4];
#pragma unroll
        for (int sub = 0; sub < 4; ++sub) {
            e0[sub] = *(const f32x4*)(ebase + (dq * 4 + sub) * KCODES);
            e1[sub] = *(const f32x4*)(ebase + (dq * 4 + sub) * KCODES + 256);
        }
#pragma unroll
        for (int sub = 0; sub < 4; ++sub) {       // fold ||e||^2 (single pass)
            sume2_0 = sume2_0 + e0[sub] * e0[sub];
            sume2_1 = sume2_1 + e1[sub] * e1[sub];
        }
#pragma unroll
        for (int r = 0; r < RPW; ++r) {
            const f32x4 xv = s_X[(rl0 + r) * 16 + dq];   // DS broadcast
            acc[r][0] = acc[r][0] + xv.x * e0[0];
            acc[r][1] = acc[r][1] + xv.x * e1[0];
            acc[r][0] = acc[r][0] + xv.y * e0[1];
            acc[r][1] = acc[r][1] + xv.y * e1[1];
            acc[r][0] = acc[r][0] + xv.z * e0[2];
            acc[r][1] = acc[r][1] + xv.z * e1[2];
            acc[r][0] = acc[r][0] + xv.w * e0[3];
            acc[r][1] = acc[r][1] + xv.w * e1[3];
        }
    }

    const f32x4* et4 = (const f32x4*)et;

    // ---- epilogue phase A (loads only): distances in-place, argmin,
    //      and ISSUE all quant gathers before any store exists ----
    int   c2a[RPW];
    f32x4 qv[RPW];
#pragma unroll
    for (int r = 0; r < RPW; ++r) {
        const float sx2 = s_sumx2[rl0 + r];
        const f32x4 dd0 = (sume2_0 + sx2) + (-2.f) * acc[r][0];
        const f32x4 dd1 = (sume2_1 + sx2) + (-2.f) * acc[r][1];
        acc[r][0] = dd0;                          // keep for the store phase
        acc[r][1] = dd1;

        float bd = fminf(fminf(fminf(dd0.x, dd0.y), fminf(dd0.z, dd0.w)),
                         fminf(fminf(dd1.x, dd1.y), fminf(dd1.z, dd1.w)));
        const int kb = lane * 4;
        int ck = 0x7fffffff;
        if (dd1.w == bd) ck = 256 + kb + 3;
        if (dd1.z == bd) ck = 256 + kb + 2;
        if (dd1.y == bd) ck = 256 + kb + 1;
        if (dd1.x == bd) ck = 256 + kb + 0;
        if (dd0.w == bd) ck = kb + 3;
        if (dd0.z == bd) ck = kb + 2;
        if (dd0.y == bd) ck = kb + 1;
        if (dd0.x == bd) ck = kb + 0;

        float fd = bd;
#pragma unroll
        for (int off = 32; off; off >>= 1)
            fd = fminf(fd, __shfl_xor(fd, off));
        int c2 = (bd == fd) ? ck : 0x7fffffff;
#pragma unroll
        for (int off = 32; off; off >>= 1) {
            const int ok = __shfl_xor(c2, off);
            c2 = ok < c2 ? ok : c2;
        }
        c2a[r] = c2;
        if (lane == 0) loss_acc += fd;            // sum_d(q-x)^2 == min dist

        // quant gather: 16 lanes x f32x4, 256 B contiguous (L2-hot)
        if (lane < 16) qv[r] = et4[c2 * 16 + lane];
    }

    // ---- epilogue phase B (stores only; nothing waits on them) ----
#pragma unroll
    for (int r = 0; r < RPW; ++r) {
        const int row = rbase + rl0 + r;
        const int c2 = c2a[r];

        f32x4* dp = (f32x4*)(out + DIST_OFF) + (size_t)row * 128;
        __builtin_nontemporal_store(acc[r][0], dp + lane);
        __builtin_nontemporal_store(acc[r][1], dp + 64 + lane);

        f32x4* ep = (f32x4*)(out + ENC_OFF) + (size_t)row * 128;
        const int cq = c2 >> 2;
        f32x4 v0 = {0.f, 0.f, 0.f, 0.f};
        f32x4 v1 = {0.f, 0.f, 0.f, 0.f};
        if (cq == lane) {
            v0.x = (c2 & 3) == 0 ? 1.f : 0.f;
            v0.y = (c2 & 3) == 1 ? 1.f : 0.f;
            v0.z = (c2 & 3) == 2 ? 1.f : 0.f;
            v0.w = (c2 & 3) == 3 ? 1.f : 0.f;
        }
        if (cq == 64 + lane) {
            v1.x = (c2 & 3) == 0 ? 1.f : 0.f;
            v1.y = (c2 & 3) == 1 ? 1.f : 0.f;
            v1.z = (c2 & 3) == 2 ? 1.f : 0.f;
            v1.w = (c2 & 3) == 3 ? 1.f : 0.f;
        }
        __builtin_nontemporal_store(v0, ep + lane);
        __builtin_nontemporal_store(v1, ep + 64 + lane);

        if (lane < 16)
            ((f32x4*)(out + QUANT_OFF + (size_t)row * DIM))[lane] = qv[r];

        if (lane == 0) {
            out[IDX_OFF + row] = (float)c2;
            atomicAdd(&hist[c2], 1);              // no-return atomic, not waited
        }
    }

    // ---- loss: deterministic per-block partial ----
    if (lane == 0) s_loss[w] = loss_acc;
    __syncthreads();
    if (tid == 0) {
        float s = 0.f;
#pragma unroll
        for (int i = 0; i < 8; ++i) s += s_loss[i];
        loss_part[blockIdx.x] = s;
    }
}

__global__ __launch_bounds__(512) void vq_final(
    const int* __restrict__ hist, const float* __restrict__ loss_part,
    float* __restrict__ out)
{
    __shared__ float s_red[8];
    __shared__ float s_red2[8];
    const int tid = threadIdx.x;
    const int w = tid >> 6, lane = tid & 63;

    float p = (float)hist[tid] * (1.f / 65536.f);
    float t = p * logf(p + 1e-10f);   // p==0 -> 0
    float l = loss_part[tid] + loss_part[tid + 512];   // 1024 partials
#pragma unroll
    for (int off = 32; off; off >>= 1) {
        t += __shfl_xor(t, off);
        l += __shfl_xor(l, off);
    }
    if (lane == 0) { s_red[w] = t; s_red2[w] = l; }
    __syncthreads();
    if (tid == 0) {
        float s = 0.f, ls = 0.f;
#pragma unroll
        for (int i = 0; i < 8; ++i) { s += s_red[i]; ls += s_red2[i]; }
        out[PERP_OFF] = expf(-s);
        // loss = (1 + 0.25) * mean((q - x)^2) over 4194304 elements
        out[LOSS_OFF] = ls * (1.25f / 4194304.f);
    }
}

extern "C" void kernel_launch(void* const* d_in, const int* in_sizes, int n_in,
                              void* d_out, int out_size, void* d_ws, size_t ws_size,
                              hipStream_t stream) {
    const float* inp = (const float*)d_in[0];
    const float* emb = (const float*)d_in[2];
    float* out = (float*)d_out;
    int*   hist      = (int*)d_ws;                     // 512 ints    @ 0
    float* loss_part = (float*)((char*)d_ws + 2048);   // 1024 floats @ 2048
    float* et        = (float*)((char*)d_ws + 8192);   // 128 KB ET   @ 8192

    (void)hipMemsetAsync(d_ws, 0, 2048, stream);       // hist only
    vq_transpose<<<dim3(8), dim3(64), 0, stream>>>(emb, et);
    vq_main<<<dim3(NBLOCKS), dim3(512), 0, stream>>>(
        inp, emb, et, out, hist, loss_part);
    vq_final<<<dim3(1), dim3(512), 0, stream>>>(hist, loss_part, out);
}